// Round 6
// baseline (249.093 us; speedup 1.0000x reference)
//
#include <hip/hip_runtime.h>
#include <cstdint>

typedef short short8 __attribute__((ext_vector_type(8)));
typedef float floatx4 __attribute__((ext_vector_type(4)));
typedef unsigned short ushortx4 __attribute__((ext_vector_type(4)));

__device__ __forceinline__ unsigned short f2bf(float f) {
  union { float f; unsigned u; } v; v.f = f;
  unsigned r = v.u + 0x7FFFu + ((v.u >> 16) & 1u);  // RNE
  return (unsigned short)(r >> 16);
}
__device__ __forceinline__ float bf2f(unsigned short h) {
  union { unsigned u; float f; } v; v.u = ((unsigned)h) << 16; return v.f;
}

#define MFMA16B(A, B, C) __builtin_amdgcn_mfma_f32_16x16x32_bf16((A), (B), (C), 0, 0, 0)
// Zero-cost compiler fence: stops TBAA-based reordering of same-wave LDS
// read-after-write through differently-typed pointers. HW DS ops are
// per-wave in-order, so no runtime sync is needed.
#define LDS_FENCE() asm volatile("" ::: "memory")

// Round fp32 weights to bf16 once per launch (d_ws is re-poisoned every call).
__global__ void __launch_bounds__(256) prep_weights(const float* __restrict__ wq,
                                                    const float* __restrict__ wp,
                                                    unsigned short* __restrict__ wq_h,
                                                    unsigned short* __restrict__ wp_h) {
  int i = blockIdx.x * 256 + threadIdx.x;
  if (i < 384 * 128) wq_h[i] = f2bf(wq[i]);
  if (i < 128 * 128) wp_h[i] = f2bf(wp[i]);
}

// One block = one window. 4 waves; wave h owns head h end-to-end (wave-private
// LDS pipeline, only 2 barriers per block, around the shared O tile).
// LDS 48KB -> 3 blocks/CU (12 waves/CU).
__global__ void __launch_bounds__(256, 3) win_attn(const float* __restrict__ x,
                                                   const unsigned short* __restrict__ wqh,
                                                   const unsigned short* __restrict__ wph,
                                                   const float* __restrict__ bias,
                                                   float* __restrict__ out) {
  // Region A (per-wave 8KB): Q cols 0..31 | K cols 32..63, [64 rows][128B],
  //   XOR-swizzled byte^=(row&7)<<4. Later aliased by P[64][64] (same swizzle).
  //   After barrier, first 17408B aliased by Os[64][136] (odd-slot pitch).
  // Region B (per-wave 4KB): Vt[32 d][64 t], same swizzle.
  __shared__ char smem[49152];

  const int tid = threadIdx.x;
  const int wv = tid >> 6;          // wave id == head id
  const int lane = tid & 63;
  const int lr = lane & 15;
  const int lg = lane >> 4;
  const int swz = (lr & 7) << 4;

  const int bid = blockIdx.x;
  const int b = bid >> 6;
  const int g = bid & 63;
  const int gh = g >> 3, gw = g & 7;
  const size_t base = (size_t)b * (4096 * 128);

  char* regA = smem + wv * 8192;           // Q|K, later P
  char* regV = smem + 32768 + wv * 4096;   // Vt
  char* osb  = smem;                       // Os [64][136] (post-barrier alias)

  const float SCALE = 0.17677669529663687f;  // 32^-0.5 (folded into Q)

  // ---- QKV projection for head wv (X hi/lo straight from global) ----
#pragma unroll
  for (int mt = 0; mt < 4; ++mt) {
    const int s = mt * 16 + lr;
    const int n = gh * 512 + (s >> 3) * 64 + gw * 8 + (s & 7);
    const float* xp = x + base + (size_t)n * 128 + lg * 8;
    short8 ah[4], al[4];
#pragma unroll
    for (int ks = 0; ks < 4; ++ks) {
      float4 u = *(const float4*)(xp + ks * 32);
      float4 w = *(const float4*)(xp + ks * 32 + 4);
      float f[8] = {u.x, u.y, u.z, u.w, w.x, w.y, w.z, w.w};
      short8 hh, ll;
#pragma unroll
      for (int j = 0; j < 8; ++j) {
        unsigned short hb = f2bf(f[j]);
        hh[j] = (short)hb;
        ll[j] = (short)f2bf(f[j] - bf2f(hb));
      }
      ah[ks] = hh;
      al[ks] = ll;
    }
#pragma unroll
    for (int m = 0; m < 3; ++m) {
#pragma unroll
      for (int jt = 0; jt < 2; ++jt) {
        floatx4 acc = {0.f, 0.f, 0.f, 0.f};
        const unsigned short* wb =
            wqh + (size_t)(m * 128 + wv * 32 + jt * 16 + lr) * 128 + lg * 8;
#pragma unroll
        for (int ks = 0; ks < 4; ++ks) {
          short8 bw = *(const short8*)(wb + ks * 32);
          acc = MFMA16B(ah[ks], bw, acc);
          acc = MFMA16B(al[ks], bw, acc);
        }
        if (m == 2) {
          // V: store transposed Vt[d][t], t contiguous (vector store)
          ushortx4 vv;
#pragma unroll
          for (int r = 0; r < 4; ++r) vv[r] = f2bf(acc[r]);
          const int d = jt * 16 + lr;
          *(ushortx4*)(regV + ((d * 128 + mt * 32 + lg * 8) ^ swz)) = vv;
        } else {
#pragma unroll
          for (int r = 0; r < 4; ++r) {
            const int s0 = mt * 16 + 4 * lg + r;
            const int col = (m ? 32 : 0) + jt * 16 + lr;
            const float v = (m == 0) ? acc[r] * SCALE : acc[r];
            *(unsigned short*)(regA + ((s0 * 128 + col * 2) ^ ((s0 & 7) << 4))) =
                f2bf(v);
          }
        }
      }
    }
  }

  LDS_FENCE();  // same-wave RAW: Q/K/V stores above, fragment reads below

  // ---- S^T[t][s] = K·Q^T (wave-private, no barrier) ----
  short8 kf[4], qf[4];
#pragma unroll
  for (int i = 0; i < 4; ++i) {
    const int row = i * 16 + lr;
    qf[i] = *(const short8*)(regA + ((row * 128 + 16 * lg) ^ swz));
    kf[i] = *(const short8*)(regA + ((row * 128 + 64 + 16 * lg) ^ swz));
  }
  floatx4 sc[4][4];
#pragma unroll
  for (int mt = 0; mt < 4; ++mt)
#pragma unroll
    for (int nt = 0; nt < 4; ++nt) {
      floatx4 z = {0.f, 0.f, 0.f, 0.f};
      sc[mt][nt] = MFMA16B(kf[mt], qf[nt], z);  // rows t=16mt+4lg+r, cols s=16nt+lr
    }

  // ---- softmax over t for each of the lane's 4 s-columns ----
  float mx[4], inv[4];
#pragma unroll
  for (int nt = 0; nt < 4; ++nt) {
    float m0 = -1e30f;
#pragma unroll
    for (int mt = 0; mt < 4; ++mt)
#pragma unroll
      for (int r = 0; r < 4; ++r) m0 = fmaxf(m0, sc[mt][nt][r]);
    m0 = fmaxf(m0, __shfl_xor(m0, 16));
    m0 = fmaxf(m0, __shfl_xor(m0, 32));
    mx[nt] = m0;
  }
#pragma unroll
  for (int nt = 0; nt < 4; ++nt) {
    float s0 = 0.f;
#pragma unroll
    for (int mt = 0; mt < 4; ++mt)
#pragma unroll
      for (int r = 0; r < 4; ++r) {
        float e = __expf(sc[mt][nt][r] - mx[nt]);
        sc[mt][nt][r] = e;
        s0 += e;
      }
    s0 += __shfl_xor(s0, 16);
    s0 += __shfl_xor(s0, 32);
    inv[nt] = 1.f / s0;
  }

  // ---- write P[s][t] over Q/K region (wave-private alias; DS in-order) ----
#pragma unroll
  for (int nt = 0; nt < 4; ++nt) {
    const int row = nt * 16 + lr;
#pragma unroll
    for (int mt = 0; mt < 4; ++mt) {
      ushortx4 pv;
#pragma unroll
      for (int r = 0; r < 4; ++r) pv[r] = f2bf(sc[mt][nt][r] * inv[nt]);
      *(ushortx4*)(regA + ((row * 128 + mt * 32 + lg * 8) ^ swz)) = pv;
    }
  }

  LDS_FENCE();  // same-wave RAW: P stores above, P/V fragment reads below

  // ---- O^T[d][s] = Vt·P^T ----
  short8 vf[2][2], pf[4][2];
#pragma unroll
  for (int dt = 0; dt < 2; ++dt)
#pragma unroll
    for (int ks = 0; ks < 2; ++ks)
      vf[dt][ks] = *(const short8*)(regV + (((16 * dt + lr) * 128 + ks * 64 + 16 * lg) ^ swz));
#pragma unroll
  for (int st = 0; st < 4; ++st)
#pragma unroll
    for (int ks = 0; ks < 2; ++ks)
      pf[st][ks] = *(const short8*)(regA + (((16 * st + lr) * 128 + ks * 64 + 16 * lg) ^ swz));
  floatx4 ot[2][4];
#pragma unroll
  for (int dt = 0; dt < 2; ++dt)
#pragma unroll
    for (int st = 0; st < 4; ++st) {
      floatx4 z = {0.f, 0.f, 0.f, 0.f};
      ot[dt][st] = z;
#pragma unroll
      for (int ks = 0; ks < 2; ++ks)
        ot[dt][st] = MFMA16B(vf[dt][ks], pf[st][ks], ot[dt][st]);
    }

  __syncthreads();  // everyone done with per-wave regions before Os overwrites

  // ---- Os[s][h*32+d] (bf16), pitch 136 shorts (odd slot count) ----
#pragma unroll
  for (int st = 0; st < 4; ++st)
#pragma unroll
    for (int dt = 0; dt < 2; ++dt) {
      ushortx4 ov;
#pragma unroll
      for (int r = 0; r < 4; ++r) ov[r] = f2bf(ot[dt][st][r]);
      *(ushortx4*)(osb + (16 * st + lr) * 272 + (wv * 32 + dt * 16 + 4 * lg) * 2) = ov;
    }

  __syncthreads();

  // ---- out-projection: wave wv does token rows 16wv..16wv+15 ----
  short8 ao[4];
#pragma unroll
  for (int ks = 0; ks < 4; ++ks)
    ao[ks] = *(const short8*)(osb + (16 * wv + lr) * 272 + ks * 64 + 16 * lg);
#pragma unroll
  for (int nt = 0; nt < 8; ++nt) {
    floatx4 acc = {0.f, 0.f, 0.f, 0.f};
    const unsigned short* wb = wph + (size_t)(nt * 16 + lr) * 128 + lg * 8;
#pragma unroll
    for (int ks = 0; ks < 4; ++ks)
      acc = MFMA16B(ao[ks], *(const short8*)(wb + ks * 32), acc);
    const float bb = bias[nt * 16 + lr];
#pragma unroll
    for (int r = 0; r < 4; ++r) {
      const int s0 = 16 * wv + 4 * lg + r;
      const int n = gh * 512 + (s0 >> 3) * 64 + gw * 8 + (s0 & 7);
      out[base + (size_t)n * 128 + nt * 16 + lr] = acc[r] + bb;
    }
  }
}

extern "C" void kernel_launch(void* const* d_in, const int* in_sizes, int n_in,
                              void* d_out, int out_size, void* d_ws, size_t ws_size,
                              hipStream_t stream) {
  (void)in_sizes; (void)n_in; (void)out_size; (void)ws_size;
  const float* x  = (const float*)d_in[0];
  const float* wq = (const float*)d_in[1];
  const float* wp = (const float*)d_in[2];
  const float* bp = (const float*)d_in[3];
  float* out = (float*)d_out;
  unsigned short* wq_h = (unsigned short*)d_ws;   // 384*128 bf16
  unsigned short* wp_h = wq_h + 384 * 128;        // 128*128 bf16
  prep_weights<<<192, 256, 0, stream>>>(wq, wp, wq_h, wp_h);
  win_attn<<<2048, 256, 0, stream>>>(x, wq_h, wp_h, bp, out);
}

// Round 10
// 223.357 us; speedup vs baseline: 1.1152x; 1.1152x over previous
//
#include <hip/hip_runtime.h>
#include <hip/hip_bf16.h>
#include <cstdint>

typedef short short8 __attribute__((ext_vector_type(8)));
typedef float floatx4 __attribute__((ext_vector_type(4)));
typedef unsigned short ushortx4 __attribute__((ext_vector_type(4)));
typedef unsigned int uintx4 __attribute__((ext_vector_type(4)));

#define MFMA16B(A, B, C) __builtin_amdgcn_mfma_f32_16x16x32_bf16((A), (B), (C), 0, 0, 0)
#define LDS_FENCE() asm volatile("" ::: "memory")

__device__ __forceinline__ unsigned short f2bf(float f) {
  union { float f; unsigned u; } v; v.f = f;
  unsigned r = v.u + 0x7FFFu + ((v.u >> 16) & 1u);
  return (unsigned short)(r >> 16);
}
// packed RNE convert: 2 floats -> 2 bf16 in one v_cvt_pk_bf16_f32
__device__ __forceinline__ unsigned pack_bf2(float a, float b) {
  __hip_bfloat162 h = __float22bfloat162_rn(float2{a, b});
  union { __hip_bfloat162 h; unsigned u; } c; c.h = h; return c.u;
}
__device__ __forceinline__ float lo_half_f(unsigned u) {  // low bf16 of pack -> f32
  union { unsigned u; float f; } c; c.u = u << 16; return c.f;
}
__device__ __forceinline__ float hi_half_f(unsigned u) {  // high bf16 of pack -> f32
  union { unsigned u; float f; } c; c.u = u & 0xffff0000u; return c.f;
}
__device__ __forceinline__ ushortx4 pack_bf4(float a, float b, float c, float d) {
  uint2 p; p.x = pack_bf2(a, b); p.y = pack_bf2(c, d);
  union { uint2 u; ushortx4 s; } v; v.u = p; return v.s;
}

__global__ void __launch_bounds__(256) prep_weights(const float* __restrict__ wq,
                                                    const float* __restrict__ wp,
                                                    unsigned short* __restrict__ wq_h,
                                                    unsigned short* __restrict__ wp_h) {
  int i = blockIdx.x * 256 + threadIdx.x;
  if (i < 384 * 128) wq_h[i] = f2bf(wq[i]);
  if (i < 128 * 128) wp_h[i] = f2bf(wp[i]);
}

// One block = one window; wave = one head end-to-end.
// LDS 48KB (3 blocks/CU), time-multiplexed:
//   phase 0-1: X [64 rows][512B = 128 bf16 hi | 128 bf16 lo], xor ((row&7)<<4)
//   phase 2-3 (after barrier): per-wave 12KB at wv*12288:
//     Q [64][64B] xor((s&3)<<4) | K at +4096 same | V^T [32][128B] at +8192 xor((d&7)<<4)
//     P [64][128B] xor((s&7)<<4) overwrites Q+K after their frags are in regs
//   phase 4 (after barrier): Os [64][272B] at 0
__global__ void __launch_bounds__(256, 3) win_attn(const float* __restrict__ x,
                                                   const unsigned short* __restrict__ wqh,
                                                   const unsigned short* __restrict__ wph,
                                                   const float* __restrict__ bias,
                                                   float* __restrict__ out) {
  __shared__ char smem[49152];
  const int tid = threadIdx.x;
  const int wv = tid >> 6, lane = tid & 63, lr = lane & 15, lg = lane >> 4;
  const int bid = blockIdx.x;
  const int b = bid >> 6, g = bid & 63, gh = g >> 3, gw = g & 7;
  const size_t base = (size_t)b * (4096 * 128);

  // ---- phase 0: stage X window once per block (hi/lo bf16, packed converts) ----
  {
    const int r = tid >> 2, c0 = (tid & 3) * 32;
    const int n = gh * 512 + (r >> 3) * 64 + gw * 8 + (r & 7);
    const float4* xp = (const float4*)(x + base + (size_t)n * 128 + c0);
    const int rb = r * 512, sz = (r & 7) << 4;
#pragma unroll
    for (int i = 0; i < 4; ++i) {
      float4 u = xp[2 * i], w = xp[2 * i + 1];
      unsigned h0 = pack_bf2(u.x, u.y), h1 = pack_bf2(u.z, u.w);
      unsigned h2 = pack_bf2(w.x, w.y), h3 = pack_bf2(w.z, w.w);
      unsigned l0 = pack_bf2(u.x - lo_half_f(h0), u.y - hi_half_f(h0));
      unsigned l1 = pack_bf2(u.z - lo_half_f(h1), u.w - hi_half_f(h1));
      unsigned l2 = pack_bf2(w.x - lo_half_f(h2), w.y - hi_half_f(h2));
      unsigned l3 = pack_bf2(w.z - lo_half_f(h3), w.w - hi_half_f(h3));
      uintx4 hv = {h0, h1, h2, h3}, lv = {l0, l1, l2, l3};
      *(uintx4*)(smem + ((rb + (c0 + 8 * i) * 2) ^ sz)) = hv;
      *(uintx4*)(smem + ((rb + 256 + (c0 + 8 * i) * 2) ^ sz)) = lv;
    }
  }
  __syncthreads();

  const int swzx = (lr & 7) << 4;
  const float SCALE = 0.17677669529663687f;  // 32^-0.5, folded into Q

  // ---- phase 1: QKV for head wv; weights hoisted, acc packed to regs ----
  ushortx4 pk[6][4];
#pragma unroll
  for (int j = 0; j < 6; ++j) {  // j = m*2+jt : Q0 Q1 K0 K1 V0 V1
    const int m = j >> 1, jt = j & 1;
    const unsigned short* wb = wqh + (size_t)(m * 128 + wv * 32 + jt * 16 + lr) * 128 + lg * 8;
    short8 bw[4];
    bw[0] = *(const short8*)(wb);
    bw[1] = *(const short8*)(wb + 32);
    bw[2] = *(const short8*)(wb + 64);
    bw[3] = *(const short8*)(wb + 96);
    const float fs = (j < 2) ? SCALE : 1.0f;
#pragma unroll
    for (int mt = 0; mt < 4; ++mt) {
      const int rbase = (16 * mt + lr) * 512 + lg * 16;
      floatx4 acc = {0.f, 0.f, 0.f, 0.f};
#pragma unroll
      for (int kk = 0; kk < 8; ++kk) {  // 0-3 hi, 4-7 lo; same weights
        short8 a = *(const short8*)(smem + ((rbase + kk * 64) ^ swzx));
        acc = MFMA16B(a, bw[kk & 3], acc);
      }
      pk[j][mt] = pack_bf4(acc[0] * fs, acc[1] * fs, acc[2] * fs, acc[3] * fs);
    }
  }
  __syncthreads();  // X dead; per-wave regions take over

  // ---- phase 1b: spill Q/K (scalar) and V^T (packed) to per-wave LDS ----
  char* const wbase = smem + wv * 12288;
#pragma unroll
  for (int j = 0; j < 4; ++j) {
    char* qk = wbase + (j >> 1) * 4096;
    const int d = (j & 1) * 16 + lr;
#pragma unroll
    for (int mt = 0; mt < 4; ++mt)
#pragma unroll
      for (int r = 0; r < 4; ++r) {
        const int s = 16 * mt + 4 * lg + r;
        *(unsigned short*)(qk + ((s * 64 + d * 2) ^ ((s & 3) << 4))) = pk[j][mt][r];
      }
  }
#pragma unroll
  for (int jt = 0; jt < 2; ++jt) {
    const int d = jt * 16 + lr;
#pragma unroll
    for (int mt = 0; mt < 4; ++mt)
      *(ushortx4*)(wbase + 8192 + ((d * 128 + (16 * mt + 4 * lg) * 2) ^ ((d & 7) << 4))) =
          pk[4 + jt][mt];
  }
  LDS_FENCE();

  // ---- phase 2: S^T[t][s] = K·Q ----
  const int swzq = (lr & 3) << 4, swzp = (lr & 7) << 4;
  short8 ka[4], qb[4];
#pragma unroll
  for (int i = 0; i < 4; ++i) {
    const int ro = (16 * i + lr) * 64 + lg * 16;
    qb[i] = *(const short8*)(wbase + (ro ^ swzq));
    ka[i] = *(const short8*)(wbase + 4096 + (ro ^ swzq));
  }
  floatx4 sc[4][4];
#pragma unroll
  for (int mt = 0; mt < 4; ++mt)
#pragma unroll
    for (int nt = 0; nt < 4; ++nt) {
      floatx4 z = {0.f, 0.f, 0.f, 0.f};
      sc[mt][nt] = MFMA16B(ka[mt], qb[nt], z);  // t = 16mt+4lg+r, s = 16nt+lr
    }

  // softmax over t per s-column (lane group {lr, lr+16, lr+32, lr+48})
  float inv[4];
#pragma unroll
  for (int nt = 0; nt < 4; ++nt) {
    float m0 = -1e30f;
#pragma unroll
    for (int mt = 0; mt < 4; ++mt)
#pragma unroll
      for (int r = 0; r < 4; ++r) m0 = fmaxf(m0, sc[mt][nt][r]);
    m0 = fmaxf(m0, __shfl_xor(m0, 16));
    m0 = fmaxf(m0, __shfl_xor(m0, 32));
    float s0 = 0.f;
#pragma unroll
    for (int mt = 0; mt < 4; ++mt)
#pragma unroll
      for (int r = 0; r < 4; ++r) {
        float e = __expf(sc[mt][nt][r] - m0);
        sc[mt][nt][r] = e;
        s0 += e;
      }
    s0 += __shfl_xor(s0, 16);
    s0 += __shfl_xor(s0, 32);
    inv[nt] = 1.f / s0;
  }

  // P[s][t] packed stores (overwrites Q+K; frags already in regs)
#pragma unroll
  for (int nt = 0; nt < 4; ++nt) {
    const int rb = (16 * nt + lr) * 128;
#pragma unroll
    for (int mt = 0; mt < 4; ++mt)
      *(ushortx4*)(wbase + ((rb + (16 * mt + 4 * lg) * 2) ^ swzp)) =
          pack_bf4(sc[mt][nt][0] * inv[nt], sc[mt][nt][1] * inv[nt],
                   sc[mt][nt][2] * inv[nt], sc[mt][nt][3] * inv[nt]);
  }
  LDS_FENCE();

  // ---- phase 3: O^T[d][s] = V^T · P^T ----
  short8 va[2][2], pb[4][2];
#pragma unroll
  for (int dt = 0; dt < 2; ++dt)
#pragma unroll
    for (int ks = 0; ks < 2; ++ks)
      va[dt][ks] = *(const short8*)(wbase + 8192 +
                   (((16 * dt + lr) * 128 + ks * 64 + lg * 16) ^ swzp));
#pragma unroll
  for (int st = 0; st < 4; ++st)
#pragma unroll
    for (int ks = 0; ks < 2; ++ks)
      pb[st][ks] = *(const short8*)(wbase +
                   (((16 * st + lr) * 128 + ks * 64 + lg * 16) ^ swzp));
  floatx4 ot[2][4];
#pragma unroll
  for (int dt = 0; dt < 2; ++dt)
#pragma unroll
    for (int st = 0; st < 4; ++st) {
      floatx4 z = {0.f, 0.f, 0.f, 0.f};
      z = MFMA16B(va[dt][0], pb[st][0], z);
      ot[dt][st] = MFMA16B(va[dt][1], pb[st][1], z);
    }

  __syncthreads();  // all P/V reads done before Os overwrites region

  // ---- Os[s][c=32wv+d], pitch 272B ----
#pragma unroll
  for (int st = 0; st < 4; ++st)
#pragma unroll
    for (int dt = 0; dt < 2; ++dt)
      *(ushortx4*)(smem + (16 * st + lr) * 272 + (wv * 32 + dt * 16 + 4 * lg) * 2) =
          pack_bf4(ot[dt][st][0], ot[dt][st][1], ot[dt][st][2], ot[dt][st][3]);
  __syncthreads();

  // ---- phase 4: out-proj, wave wv owns token rows 16wv..+15 ----
  short8 ao[4];
#pragma unroll
  for (int kk = 0; kk < 4; ++kk)
    ao[kk] = *(const short8*)(smem + (16 * wv + lr) * 272 + kk * 64 + lg * 16);
#pragma unroll
  for (int nt = 0; nt < 8; ++nt) {
    const unsigned short* wb = wph + (size_t)(nt * 16 + lr) * 128 + lg * 8;
    floatx4 acc = {0.f, 0.f, 0.f, 0.f};
    acc = MFMA16B(ao[0], *(const short8*)(wb), acc);
    acc = MFMA16B(ao[1], *(const short8*)(wb + 32), acc);
    acc = MFMA16B(ao[2], *(const short8*)(wb + 64), acc);
    acc = MFMA16B(ao[3], *(const short8*)(wb + 96), acc);
    const float bb = bias[nt * 16 + lr];
#pragma unroll
    for (int r = 0; r < 4; ++r) {
      const int s0 = 16 * wv + 4 * lg + r;
      const int n = gh * 512 + (s0 >> 3) * 64 + gw * 8 + (s0 & 7);
      out[base + (size_t)n * 128 + nt * 16 + lr] = acc[r] + bb;
    }
  }
}

extern "C" void kernel_launch(void* const* d_in, const int* in_sizes, int n_in,
                              void* d_out, int out_size, void* d_ws, size_t ws_size,
                              hipStream_t stream) {
  (void)in_sizes; (void)n_in; (void)out_size; (void)ws_size;
  const float* x  = (const float*)d_in[0];
  const float* wq = (const float*)d_in[1];
  const float* wp = (const float*)d_in[2];
  const float* bp = (const float*)d_in[3];
  float* out = (float*)d_out;
  unsigned short* wq_h = (unsigned short*)d_ws;   // 384*128 bf16
  unsigned short* wp_h = wq_h + 384 * 128;        // 128*128 bf16
  prep_weights<<<192, 256, 0, stream>>>(wq, wp, wq_h, wp_h);
  win_attn<<<2048, 256, 0, stream>>>(x, wq_h, wp_h, bp, out);
}